// Round 6
// baseline (149.556 us; speedup 1.0000x reference)
//
#include <hip/hip_runtime.h>
#include <math.h>

#define NB 4
#define HH 16
#define SS 1024
#define DD 64
#define NKST 16   // SS / 64

typedef __attribute__((ext_vector_type(8))) short bf16x8;
typedef __attribute__((ext_vector_type(4))) float f32x4;

static __device__ __forceinline__ short f2bf(float f) {
    __bf16 h = (__bf16)f;
    return __builtin_bit_cast(short, h);
}
static __device__ __forceinline__ float bflo(int w) {
    return __builtin_bit_cast(float, (unsigned)w << 16);
}
static __device__ __forceinline__ float bfhi(int w) {
    return __builtin_bit_cast(float, (unsigned)w & 0xffff0000u);
}
static __device__ __forceinline__ float bfu(unsigned short u) {
    return __builtin_bit_cast(float, (unsigned)u << 16);
}
// P LDS: [pos = q*64 + k][8 u32 head-pairs], XOR swizzle.
// writer 2-way (free), phase-1.5 reader conflict-free.
static __device__ __forceinline__ int pidx(int pos, int hp) {
    int s = ((pos >> 2) & 3) | (((pos >> 9) & 1) << 2);
    return pos * 8 + (hp ^ s);
}
// M LDS: [16 g][16 q x 32 k-pairs u32], XOR on 16B groups.
// writer b64 ~min, reader b128 uniform 8 lanes/bank-group (min).
static __device__ __forceinline__ int midx(int g, int loc, int x3) {
    return g * 512 + ((((loc >> 2) ^ x3) << 2) | (loc & 3));
}

static __device__ __forceinline__ bf16x8 load8_bf16(const float* p) {
    const float4* p4 = reinterpret_cast<const float4*>(p);
    float4 a = p4[0], b = p4[1];
    bf16x8 f;
    f[0]=f2bf(a.x); f[1]=f2bf(a.y); f[2]=f2bf(a.z); f[3]=f2bf(a.w);
    f[4]=f2bf(b.x); f[5]=f2bf(b.y); f[6]=f2bf(b.z); f[7]=f2bf(b.w);
    return f;
}

// ---------- prep: K -> fragment-major bf16 ----------
__global__ __launch_bounds__(256) void prep_kfrag(const float* __restrict__ xk,
                                                  short* __restrict__ kfr) {
    int c = blockIdx.x * 256 + threadIdx.x;
    int lane = c & 63, ds = (c >> 6) & 1, kt = (c >> 7) & 3;
    int kst = (c >> 9) & 15, h = (c >> 13) & 15, b = c >> 17;
    const float* src = xk + ((size_t)((b * HH + h) * SS) + kst * 64 + kt * 16 + (lane & 15)) * DD
                          + ds * 32 + (lane >> 4) * 8;
    *(reinterpret_cast<bf16x8*>(kfr) + c) = load8_bf16(src);
}

// ---------- prep: V -> fragment-major bf16 (transposed) ----------
__global__ __launch_bounds__(256) void prep_vfrag(const float* __restrict__ xv,
                                                  short* __restrict__ vfr) {
    __shared__ float T[64][65];
    int tile = blockIdx.x;                 // (b*16+h)*16 + kst
    int t = threadIdx.x;
    const float* src = xv + ((size_t)(tile >> 4) * SS + (tile & 15) * 64) * DD;
    int row = t >> 2, col = (t & 3) * 16;
#pragma unroll
    for (int ii = 0; ii < 4; ++ii) {
        float4 v = *reinterpret_cast<const float4*>(src + row * DD + col + ii * 4);
        T[row][col + ii*4] = v.x; T[row][col + ii*4 + 1] = v.y;
        T[row][col + ii*4 + 2] = v.z; T[row][col + ii*4 + 3] = v.w;
    }
    __syncthreads();
#pragma unroll
    for (int jj = 0; jj < 2; ++jj) {
        int c2 = t * 2 + jj;
        int lane = c2 & 63, nt = (c2 >> 6) & 3, kc = (c2 >> 8) & 1;
        bf16x8 o;
#pragma unroll
        for (int i = 0; i < 8; ++i)
            o[i] = f2bf(T[kc * 32 + (lane >> 4) * 8 + i][nt * 16 + (lane & 15)]);
        *(reinterpret_cast<bf16x8*>(vfr) + (size_t)tile * 512 + c2) = o;
    }
}

// One block = (b, qt, kpar). 8 waves. Block handles kst = kpar, kpar+2, ...
//  phase1  : wave w: QK^T heads {2w,2w+1} (all 16 heads covered, NO duplication)
//  phase1.5: mix MFMA -> M for all 16 g
//  phase2  : wave w: softmax + PV for g = 2w, 2w+1 -> bf16 partial O + (m,l)
__global__ __launch_bounds__(512, 4) void hca_fused(
    const float* __restrict__ xq, const short* __restrict__ kfr,
    const short* __restrict__ vfr, const float* __restrict__ Wm,
    const int* __restrict__ causalp, unsigned short* __restrict__ ppO,
    float2* __restrict__ ppml)
{
    __shared__ int Pbuf[8192];   // 32 KB
    __shared__ int Mbuf[8192];   // 32 KB

    const int tid  = threadIdx.x;
    const int lane = tid & 63;
    const int w    = tid >> 6;     // 0..7
    const int l15  = lane & 15;
    const int lg   = lane >> 4;

    // bid<256: kpar=0, qt descending (long first); bid>=256: kpar=1, qt ascending.
    // CU c gets bids c, c+256 -> (qt, kpar0)+(63-qt, kpar1): work sum ~const.
    const int bid  = blockIdx.x;
    const int j    = bid & 255;
    const int kpar = bid >> 8;
    const int b    = j & 3;
    const int i    = j >> 2;
    const int qt   = kpar ? i : 63 - i;
    const int q0   = qt << 4;
    const int pairIdx = b * 64 + qt;

    const int causal = causalp[0];
    const float LOG2E = 1.44269504088896f;

    // W B-frag for mix MFMA (K=16 used, zero-padded)
    bf16x8 wt = {0,0,0,0,0,0,0,0};
    if (lg < 2) {
#pragma unroll
        for (int ii = 0; ii < 8; ++ii)
            wt[ii] = f2bf(Wm[l15 * 16 + lg * 8 + ii] * 0.125f * LOG2E);
    }

    // Q A-frags for phase-1 heads (2w, 2w+1)
    bf16x8 qf[2][2];
#pragma unroll
    for (int hi = 0; hi < 2; ++hi) {
        const float* qp = xq + ((size_t)(b * HH + 2 * w + hi) * SS + q0 + l15) * DD + lg * 8;
#pragma unroll
        for (int ds = 0; ds < 2; ++ds) qf[hi][ds] = load8_bf16(qp + ds * 32);
    }

    f32x4 oacc[2][4];
#pragma unroll
    for (int gi = 0; gi < 2; ++gi)
#pragma unroll
        for (int nt = 0; nt < 4; ++nt) oacc[gi][nt] = (f32x4){0.f, 0.f, 0.f, 0.f};
    float mrun[2] = {-INFINITY, -INFINITY};
    float lrun[2] = {0.f, 0.f};

    const int nk = causal ? ((q0 + 16 + 63) >> 6) : NKST;

    for (int kst = kpar; kst < nk; kst += 2) {
        const int k0 = kst << 6;

        // ---------- phase1: QK^T, heads 2w & 2w+1, coalesced frag loads ----------
        const short* kbase = kfr + ((size_t)((b * HH + 2 * w) * NKST + kst) * 8) * 512 + lane * 8;
        __builtin_amdgcn_s_setprio(1);
#pragma unroll
        for (int kt = 0; kt < 4; ++kt) {
            f32x4 a0 = (f32x4){0.f,0.f,0.f,0.f}, a1 = a0;
#pragma unroll
            for (int ds = 0; ds < 2; ++ds) {
                bf16x8 kfa = *reinterpret_cast<const bf16x8*>(kbase + (kt*2 + ds) * 512);
                bf16x8 kfb = *reinterpret_cast<const bf16x8*>(kbase + (NKST*8 + kt*2 + ds) * 512);
                a0 = __builtin_amdgcn_mfma_f32_16x16x32_bf16(qf[0][ds], kfa, a0, 0, 0, 0);
                a1 = __builtin_amdgcn_mfma_f32_16x16x32_bf16(qf[1][ds], kfb, a1, 0, 0, 0);
            }
#pragma unroll
            for (int r = 0; r < 4; ++r) {
                int pos = (lg * 4 + r) * 64 + kt * 16 + l15;
                int pk = (int)(unsigned short)f2bf(a0[r]) | ((int)(unsigned short)f2bf(a1[r]) << 16);
                Pbuf[pidx(pos, w)] = pk;
            }
        }
        __builtin_amdgcn_s_setprio(0);
        __syncthreads();   // sync1: P ready (also orders prev phase2 M-reads vs M-writes)

        // ---------- phase1.5: head-mix MFMA, all 16 g stored ----------
#pragma unroll
        for (int m = 0; m < 8; ++m) {
            const int c = w * 8 + m;               // 16-pos chunk; q = c>>2
            const int pos = c * 16 + l15;
            int4 ia = {0, 0, 0, 0};
            if (lg < 2) {
                ia.x = Pbuf[pidx(pos, lg * 4 + 0)];
                ia.y = Pbuf[pidx(pos, lg * 4 + 1)];
                ia.z = Pbuf[pidx(pos, lg * 4 + 2)];
                ia.w = Pbuf[pidx(pos, lg * 4 + 3)];
            }
            bf16x8 A = __builtin_bit_cast(bf16x8, ia);
            f32x4 cc = (f32x4){0.f, 0.f, 0.f, 0.f};
            cc = __builtin_amdgcn_mfma_f32_16x16x32_bf16(A, wt, cc, 0, 0, 0);
            // lane: g = l15; q = c>>2, k = (c&3)*16 + lg*4 + r
            int q = c >> 2;
            int loc = q * 32 + (c & 3) * 8 + lg * 2;
            int x3 = (q + l15) & 7;
            int u0 = (int)(unsigned short)f2bf(cc[0]) | ((int)(unsigned short)f2bf(cc[1]) << 16);
            int u1 = (int)(unsigned short)f2bf(cc[2]) | ((int)(unsigned short)f2bf(cc[3]) << 16);
            *reinterpret_cast<int2*>(&Mbuf[midx(l15, loc, x3)]) = make_int2(u0, u1);
        }
        __syncthreads();   // sync2: M ready

        // ---------- phase2: softmax (log2) + PV for g = 2w, 2w+1 ----------
#pragma unroll
        for (int gi = 0; gi < 2; ++gi) {
            const int g = 2 * w + gi;

            // V frag loads (coalesced): in flight during M-read + softmax
            const short* vbase = vfr + ((size_t)((b * HH + g) * NKST + kst) * 8) * 512 + lane * 8;
            bf16x8 vf[8];
#pragma unroll
            for (int kc = 0; kc < 2; ++kc)
#pragma unroll
                for (int nt = 0; nt < 4; ++nt)
                    vf[kc * 4 + nt] = *reinterpret_cast<const bf16x8*>(vbase + (kc*4 + nt) * 512);

            const int x3r = (l15 + g) & 7;
            int4 rA = *reinterpret_cast<const int4*>(&Mbuf[midx(g, l15 * 32 + lg * 4, x3r)]);
            int4 rB = *reinterpret_cast<const int4*>(&Mbuf[midx(g, l15 * 32 + 16 + lg * 4, x3r)]);

            float sm[16];
#pragma unroll
            for (int jj = 0; jj < 4; ++jj) {
                sm[2*jj]     = bflo(rA[jj]);  sm[2*jj + 1] = bfhi(rA[jj]);
                sm[8 + 2*jj] = bflo(rB[jj]);  sm[9 + 2*jj] = bfhi(rB[jj]);
            }
            if (causal && kst == nk - 1) {
#pragma unroll
                for (int jj = 0; jj < 16; ++jj) {
                    int kk = (jj < 8) ? (lg * 8 + jj) : (32 + lg * 8 + (jj - 8));
                    if (k0 + kk > q0 + l15) sm[jj] = -INFINITY;
                }
            }

            float mx[4];
#pragma unroll
            for (int t = 0; t < 4; ++t)
                mx[t] = fmaxf(fmaxf(sm[4*t], sm[4*t+1]), fmaxf(sm[4*t+2], sm[4*t+3]));
            float mt = fmaxf(fmaxf(mx[0], mx[1]), fmaxf(mx[2], mx[3]));
            mt = fmaxf(mt, __shfl_xor(mt, 16));
            mt = fmaxf(mt, __shfl_xor(mt, 32));

            if (__any(mt > mrun[gi] + 8.0f)) {            // defer-rescale
                float mnew = fmaxf(mrun[gi], mt);
                float scl = __builtin_amdgcn_exp2f(mrun[gi] - mnew);
                mrun[gi] = mnew;
                lrun[gi] *= scl;
                int scli = __builtin_bit_cast(int, scl);
#pragma unroll
                for (int r = 0; r < 4; ++r) {
                    int v = __builtin_amdgcn_ds_bpermute((lg * 4 + r) * 4, scli);
                    float s = __builtin_bit_cast(float, v);
#pragma unroll
                    for (int nt = 0; nt < 4; ++nt) oacc[gi][nt][r] *= s;
                }
            }

            float p[16];
#pragma unroll
            for (int jj = 0; jj < 16; ++jj) p[jj] = __builtin_amdgcn_exp2f(sm[jj] - mrun[gi]);
            float s0 = ((p[0]+p[1]) + (p[2]+p[3])) + ((p[4]+p[5]) + (p[6]+p[7]));
            float s1 = ((p[8]+p[9]) + (p[10]+p[11])) + ((p[12]+p[13]) + (p[14]+p[15]));
            lrun[gi] += s0 + s1;

            int paw[8];
#pragma unroll
            for (int t = 0; t < 8; ++t)
                paw[t] = (int)(unsigned short)f2bf(p[2*t]) | ((int)(unsigned short)f2bf(p[2*t+1]) << 16);
            bf16x8 pa0 = __builtin_bit_cast(bf16x8, *(int4*)&paw[0]);
            bf16x8 pa1 = __builtin_bit_cast(bf16x8, *(int4*)&paw[4]);

            __builtin_amdgcn_s_setprio(1);
#pragma unroll
            for (int nt = 0; nt < 4; ++nt) {
                oacc[gi][nt] = __builtin_amdgcn_mfma_f32_16x16x32_bf16(pa0, vf[nt], oacc[gi][nt], 0, 0, 0);
                oacc[gi][nt] = __builtin_amdgcn_mfma_f32_16x16x32_bf16(pa1, vf[4 + nt], oacc[gi][nt], 0, 0, 0);
            }
            __builtin_amdgcn_s_setprio(0);
        }
        // no trailing barrier (sync1 of t+1 fences M-reads vs M-writes)
    }

    // ---------- epilogue: write normalized bf16 partial O + (m,l) ----------
#pragma unroll
    for (int gi = 0; gi < 2; ++gi) {
        const int g = 2 * w + gi;
        float lt = lrun[gi];
        lt += __shfl_xor(lt, 16);
        lt += __shfl_xor(lt, 32);
        if (lg == 0)
            ppml[(((size_t)pairIdx * 2 + kpar) * 16 + g) * 16 + l15] = make_float2(mrun[gi], lt);
        float rl = (lt > 0.f) ? (1.0f / lt) : 0.f;
        int rli = __builtin_bit_cast(int, rl);
        size_t obase = (((size_t)pairIdx * 2 + kpar) * 16 + g) * 1024;
#pragma unroll
        for (int r = 0; r < 4; ++r) {
            int v = __builtin_amdgcn_ds_bpermute((lg * 4 + r) * 4, rli);
            float linv = __builtin_bit_cast(float, v);
            int q = lg * 4 + r;
#pragma unroll
            for (int nt = 0; nt < 4; ++nt)
                ppO[obase + q * 64 + nt * 16 + l15] =
                    (unsigned short)f2bf(oacc[gi][nt][r] * linv);
        }
    }
}

// ---------- combine: merge the 2 k-parity partials per (b,qt) ----------
__global__ __launch_bounds__(256) void hca_combine(
    const unsigned short* __restrict__ ppO, const float2* __restrict__ ppml,
    float* __restrict__ out)
{
    const int pairIdx = blockIdx.x;        // b*64 + qt
    const int b = pairIdx >> 6, qt = pairIdx & 63;
    const int t = threadIdx.x;
    const int g = t >> 4, dc = t & 15;

    const size_t o0 = (((size_t)pairIdx * 2 + 0) * 16 + g) * 1024;
    const size_t o1 = (((size_t)pairIdx * 2 + 1) * 16 + g) * 1024;
    const float2* ml0p = ppml + (((size_t)pairIdx * 2 + 0) * 16 + g) * 16;
    const float2* ml1p = ppml + (((size_t)pairIdx * 2 + 1) * 16 + g) * 16;

#pragma unroll 4
    for (int q = 0; q < 16; ++q) {
        float2 ml0 = ml0p[q], ml1 = ml1p[q];
        float ms = fmaxf(ml0.x, ml1.x);
        float w0 = ml0.y * exp2f(ml0.x - ms);
        float w1 = ml1.y * exp2f(ml1.x - ms);
        float rs = 1.0f / (w0 + w1);
        float a0 = w0 * rs, a1 = w1 * rs;
        ushort4 u0 = *reinterpret_cast<const ushort4*>(ppO + o0 + q * 64 + dc * 4);
        ushort4 u1 = *reinterpret_cast<const ushort4*>(ppO + o1 + q * 64 + dc * 4);
        float4 res;
        res.x = a0 * bfu(u0.x) + a1 * bfu(u1.x);
        res.y = a0 * bfu(u0.y) + a1 * bfu(u1.y);
        res.z = a0 * bfu(u0.z) + a1 * bfu(u1.z);
        res.w = a0 * bfu(u0.w) + a1 * bfu(u1.w);
        *reinterpret_cast<float4*>(out + (((size_t)b * SS + qt * 16 + q) * HH + g) * DD + dc * 4) = res;
    }
}

extern "C" void kernel_launch(void* const* d_in, const int* in_sizes, int n_in,
                              void* d_out, int out_size, void* d_ws, size_t ws_size,
                              hipStream_t stream) {
    const float* xq = (const float*)d_in[0];
    const float* xk = (const float*)d_in[1];
    const float* xv = (const float*)d_in[2];
    const float* Wm = (const float*)d_in[3];
    const int* causal = (const int*)d_in[4];
    float* out = (float*)d_out;

    short* vfr = (short*)d_ws;                               // 8 MB fragment-major V
    short* kfr = vfr + (size_t)NB * HH * SS * DD;            // 8 MB fragment-major K
    unsigned short* ppO = (unsigned short*)(kfr + (size_t)NB * HH * SS * DD);  // 16 MB
    float2* ppml = (float2*)(ppO + (size_t)512 * 16 * 1024); // 1 MB

    prep_kfrag<<<2048, 256, 0, stream>>>(xk, kfr);
    prep_vfrag<<<NB * HH * NKST, 256, 0, stream>>>(xv, vfr);

    hca_fused<<<512, 512, 0, stream>>>(xq, kfr, vfr, Wm, causal, ppO, ppml);
    hca_combine<<<256, 256, 0, stream>>>(ppO, ppml, out);
}

// Round 7
// 78.419 us; speedup vs baseline: 1.9071x; 1.9071x over previous
//
#include <hip/hip_runtime.h>
#include <math.h>

#define NB 4
#define HH 16
#define SS 1024
#define DD 64
#define NKST 16   // SS / 64

typedef __attribute__((ext_vector_type(8))) short bf16x8;
typedef __attribute__((ext_vector_type(4))) float f32x4;

static __device__ __forceinline__ short f2bf(float f) {
    __bf16 h = (__bf16)f;
    return __builtin_bit_cast(short, h);
}
static __device__ __forceinline__ float bflo(int w) {
    return __builtin_bit_cast(float, (unsigned)w << 16);
}
static __device__ __forceinline__ float bfhi(int w) {
    return __builtin_bit_cast(float, (unsigned)w & 0xffff0000u);
}
static __device__ __forceinline__ float bfu(unsigned short u) {
    return __builtin_bit_cast(float, (unsigned)u << 16);
}
// P LDS: [pos = q*64 + k][8 u32 head-pairs], XOR swizzle.
static __device__ __forceinline__ int pidx(int pos, int hp) {
    int s = ((pos >> 2) & 3) | (((pos >> 9) & 1) << 2);
    return pos * 8 + (hp ^ s);
}
// M LDS: [16 g][16 q x 32 k-pairs u32], XOR on 16B groups.
static __device__ __forceinline__ int midx(int g, int loc, int x3) {
    return g * 512 + ((((loc >> 2) ^ x3) << 2) | (loc & 3));
}

static __device__ __forceinline__ bf16x8 load8_bf16(const float* p) {
    const float4* p4 = reinterpret_cast<const float4*>(p);
    float4 a = p4[0], b = p4[1];
    bf16x8 f;
    f[0]=f2bf(a.x); f[1]=f2bf(a.y); f[2]=f2bf(a.z); f[3]=f2bf(a.w);
    f[4]=f2bf(b.x); f[5]=f2bf(b.y); f[6]=f2bf(b.z); f[7]=f2bf(b.w);
    return f;
}

// ---------- prep: K -> fragment-major bf16 ----------
__global__ __launch_bounds__(256) void prep_kfrag(const float* __restrict__ xk,
                                                  short* __restrict__ kfr) {
    int c = blockIdx.x * 256 + threadIdx.x;
    int lane = c & 63, ds = (c >> 6) & 1, kt = (c >> 7) & 3;
    int kst = (c >> 9) & 15, h = (c >> 13) & 15, b = c >> 17;
    const float* src = xk + ((size_t)((b * HH + h) * SS) + kst * 64 + kt * 16 + (lane & 15)) * DD
                          + ds * 32 + (lane >> 4) * 8;
    *(reinterpret_cast<bf16x8*>(kfr) + c) = load8_bf16(src);
}

// ---------- prep: V -> fragment-major bf16 (transposed) ----------
__global__ __launch_bounds__(256) void prep_vfrag(const float* __restrict__ xv,
                                                  short* __restrict__ vfr) {
    __shared__ float T[64][65];
    int tile = blockIdx.x;                 // (b*16+h)*16 + kst
    int t = threadIdx.x;
    const float* src = xv + ((size_t)(tile >> 4) * SS + (tile & 15) * 64) * DD;
    int row = t >> 2, col = (t & 3) * 16;
#pragma unroll
    for (int ii = 0; ii < 4; ++ii) {
        float4 v = *reinterpret_cast<const float4*>(src + row * DD + col + ii * 4);
        T[row][col + ii*4] = v.x; T[row][col + ii*4 + 1] = v.y;
        T[row][col + ii*4 + 2] = v.z; T[row][col + ii*4 + 3] = v.w;
    }
    __syncthreads();
#pragma unroll
    for (int jj = 0; jj < 2; ++jj) {
        int c2 = t * 2 + jj;
        int lane = c2 & 63, nt = (c2 >> 6) & 3, kc = (c2 >> 8) & 1;
        bf16x8 o;
#pragma unroll
        for (int i = 0; i < 8; ++i)
            o[i] = f2bf(T[kc * 32 + (lane >> 4) * 8 + i][nt * 16 + (lane & 15)]);
        *(reinterpret_cast<bf16x8*>(vfr) + (size_t)tile * 512 + c2) = o;
    }
}

// One block = (b, qt-pair pp, kpar), 16 waves. Processes qt=63-pp then qt=pp,
// k-steps of parity kpar only (explicitly balanced: ~8-9 steps per block, and
// phase1+mix computed ONCE per (b,qt,kst) -- no half-duplication).
//  phase1  : wave w (hp=w&7, kh=w>>3): QK^T heads {2hp,2hp+1}, kt in {2kh,2kh+1} -> P
//  phase1.5: wave w: mix MFMA for q-row w (4 chunks) -> M (all 16 g)
//  phase2  : wave w: softmax + PV for g=w -> bf16 partial O + (m,l)
__global__ __launch_bounds__(1024, 1) void hca_fused(
    const float* __restrict__ xq, const short* __restrict__ kfr,
    const short* __restrict__ vfr, const float* __restrict__ Wm,
    const int* __restrict__ causalp, unsigned short* __restrict__ ppO,
    float2* __restrict__ ppml)
{
    __shared__ int Pbuf[8192];   // 32 KB
    __shared__ int Mbuf[8192];   // 32 KB

    const int tid  = threadIdx.x;
    const int lane = tid & 63;
    const int w    = tid >> 6;     // 0..15
    const int l15  = lane & 15;
    const int lg   = lane >> 4;

    const int bid  = blockIdx.x;           // 256 blocks: b(2) | pp(5) | kpar(1)
    const int b    = bid & 3;              // b fixed per XCD (bid%8 -> b=bid&3)
    const int pp   = (bid >> 2) & 31;
    const int kpar = (bid >> 7) & 1;

    const int causal = causalp[0];
    const int hp = w & 7;          // phase-1 head pair
    const int kh = w >> 3;         // phase-1 kt half
    const int g  = w;              // phase-2 output head

    const float LOG2E = 1.44269504088896f;

    // W B-frag for mix MFMA (K=16 used, zero-padded)
    bf16x8 wt = {0,0,0,0,0,0,0,0};
    if (lg < 2) {
#pragma unroll
        for (int ii = 0; ii < 8; ++ii)
            wt[ii] = f2bf(Wm[l15 * 16 + lg * 8 + ii] * 0.125f * LOG2E);
    }

    const short* vb0 = vfr + (size_t)(b * HH + g) * NKST * 8 * 512 + lane * 8;
    const short* kb0 = kfr + (size_t)(b * HH + 2 * hp) * NKST * 8 * 512 + lane * 8;

#pragma unroll 1
    for (int seg = 0; seg < 2; ++seg) {
        const int qt = seg ? pp : 63 - pp;
        const int q0 = qt << 4;
        const int pairIdx = b * 64 + qt;

        // Q A-frags for phase-1 heads (2hp, 2hp+1)
        bf16x8 qf[2][2];
#pragma unroll
        for (int hi = 0; hi < 2; ++hi) {
            const float* qp = xq + ((size_t)(b * HH + 2 * hp + hi) * SS + q0 + l15) * DD + lg * 8;
#pragma unroll
            for (int ds = 0; ds < 2; ++ds) qf[hi][ds] = load8_bf16(qp + ds * 32);
        }

        f32x4 oacc[4];
#pragma unroll
        for (int nt = 0; nt < 4; ++nt) oacc[nt] = (f32x4){0.f, 0.f, 0.f, 0.f};
        float mrun = -INFINITY, lrun = 0.f;

        const int nkf = causal ? ((q0 + 16 + 63) >> 6) : NKST;

#pragma unroll 1
        for (int kst = kpar; kst < nkf; kst += 2) {
            const int k0 = kst << 6;

            // ---------- phase1: QK^T heads 2hp,2hp+1, kt = 2kh, 2kh+1 ----------
            const short* kbase = kb0 + (size_t)kst * 8 * 512;
            __builtin_amdgcn_s_setprio(1);
#pragma unroll
            for (int kt2 = 0; kt2 < 2; ++kt2) {
                const int kt = kh * 2 + kt2;
                f32x4 a0 = (f32x4){0.f,0.f,0.f,0.f}, a1 = a0;
#pragma unroll
                for (int ds = 0; ds < 2; ++ds) {
                    bf16x8 kfa = *reinterpret_cast<const bf16x8*>(kbase + (kt*2 + ds) * 512);
                    bf16x8 kfb = *reinterpret_cast<const bf16x8*>(kbase + (NKST*8 + kt*2 + ds) * 512);
                    a0 = __builtin_amdgcn_mfma_f32_16x16x32_bf16(qf[0][ds], kfa, a0, 0, 0, 0);
                    a1 = __builtin_amdgcn_mfma_f32_16x16x32_bf16(qf[1][ds], kfb, a1, 0, 0, 0);
                }
#pragma unroll
                for (int r = 0; r < 4; ++r) {
                    int pos = (lg * 4 + r) * 64 + kt * 16 + l15;
                    int pk = (int)(unsigned short)f2bf(a0[r]) | ((int)(unsigned short)f2bf(a1[r]) << 16);
                    Pbuf[pidx(pos, hp)] = pk;
                }
            }
            __builtin_amdgcn_s_setprio(0);

            // V prefetch (coalesced; lands during mix + barriers)
            const short* vbase = vb0 + (size_t)kst * 8 * 512;
            bf16x8 vf[8];
#pragma unroll
            for (int kc = 0; kc < 2; ++kc)
#pragma unroll
                for (int nt = 0; nt < 4; ++nt)
                    vf[kc * 4 + nt] = *reinterpret_cast<const bf16x8*>(vbase + (kc*4 + nt) * 512);

            __syncthreads();   // sync1: P ready (also fences prev phase2 M-reads)

            // ---------- phase1.5: head-mix MFMA; wave w -> q-row w ----------
#pragma unroll
            for (int m = 0; m < 4; ++m) {
                const int c = w * 4 + m;           // pos chunk; q = c>>2 = w
                const int pos = c * 16 + l15;
                int4 ia = {0, 0, 0, 0};
                if (lg < 2) {
                    ia.x = Pbuf[pidx(pos, lg * 4 + 0)];
                    ia.y = Pbuf[pidx(pos, lg * 4 + 1)];
                    ia.z = Pbuf[pidx(pos, lg * 4 + 2)];
                    ia.w = Pbuf[pidx(pos, lg * 4 + 3)];
                }
                bf16x8 A = __builtin_bit_cast(bf16x8, ia);
                f32x4 cc = (f32x4){0.f, 0.f, 0.f, 0.f};
                cc = __builtin_amdgcn_mfma_f32_16x16x32_bf16(A, wt, cc, 0, 0, 0);
                // lane: g = l15; q = w, k = (c&3)*16 + lg*4 + r
                int loc = w * 32 + (c & 3) * 8 + lg * 2;
                int x3 = (w + l15) & 7;
                int u0 = (int)(unsigned short)f2bf(cc[0]) | ((int)(unsigned short)f2bf(cc[1]) << 16);
                int u1 = (int)(unsigned short)f2bf(cc[2]) | ((int)(unsigned short)f2bf(cc[3]) << 16);
                *reinterpret_cast<int2*>(&Mbuf[midx(l15, loc, x3)]) = make_int2(u0, u1);
            }
            __syncthreads();   // sync2: M ready

            // ---------- phase2: softmax (log2) + PV for head g = w ----------
            const int x3r = (l15 + g) & 7;
            int4 rA = *reinterpret_cast<const int4*>(&Mbuf[midx(g, l15 * 32 + lg * 4, x3r)]);
            int4 rB = *reinterpret_cast<const int4*>(&Mbuf[midx(g, l15 * 32 + 16 + lg * 4, x3r)]);

            float sm[16];
#pragma unroll
            for (int jj = 0; jj < 4; ++jj) {
                sm[2*jj]     = bflo(rA[jj]);  sm[2*jj + 1] = bfhi(rA[jj]);
                sm[8 + 2*jj] = bflo(rB[jj]);  sm[9 + 2*jj] = bfhi(rB[jj]);
            }
            if (causal && kst == nkf - 1) {
#pragma unroll
                for (int jj = 0; jj < 16; ++jj) {
                    int kk = (jj < 8) ? (lg * 8 + jj) : (32 + lg * 8 + (jj - 8));
                    if (k0 + kk > q0 + l15) sm[jj] = -INFINITY;
                }
            }

            float mx[4];
#pragma unroll
            for (int t = 0; t < 4; ++t)
                mx[t] = fmaxf(fmaxf(sm[4*t], sm[4*t+1]), fmaxf(sm[4*t+2], sm[4*t+3]));
            float mt = fmaxf(fmaxf(mx[0], mx[1]), fmaxf(mx[2], mx[3]));
            mt = fmaxf(mt, __shfl_xor(mt, 16));
            mt = fmaxf(mt, __shfl_xor(mt, 32));

            if (__any(mt > mrun + 8.0f)) {            // defer-rescale
                float mnew = fmaxf(mrun, mt);
                float scl = __builtin_amdgcn_exp2f(mrun - mnew);
                mrun = mnew;
                lrun *= scl;
                int scli = __builtin_bit_cast(int, scl);
#pragma unroll
                for (int r = 0; r < 4; ++r) {
                    int v = __builtin_amdgcn_ds_bpermute((lg * 4 + r) * 4, scli);
                    float s = __builtin_bit_cast(float, v);
#pragma unroll
                    for (int nt = 0; nt < 4; ++nt) oacc[nt][r] *= s;
                }
            }

#pragma unroll
            for (int jj = 0; jj < 16; ++jj) sm[jj] = __builtin_amdgcn_exp2f(sm[jj] - mrun);
            float s0 = ((sm[0]+sm[1]) + (sm[2]+sm[3])) + ((sm[4]+sm[5]) + (sm[6]+sm[7]));
            float s1 = ((sm[8]+sm[9]) + (sm[10]+sm[11])) + ((sm[12]+sm[13]) + (sm[14]+sm[15]));
            lrun += s0 + s1;

            int paw[8];
#pragma unroll
            for (int t = 0; t < 8; ++t)
                paw[t] = (int)(unsigned short)f2bf(sm[2*t]) | ((int)(unsigned short)f2bf(sm[2*t+1]) << 16);
            bf16x8 pa0 = __builtin_bit_cast(bf16x8, *(int4*)&paw[0]);
            bf16x8 pa1 = __builtin_bit_cast(bf16x8, *(int4*)&paw[4]);

            __builtin_amdgcn_s_setprio(1);
#pragma unroll
            for (int nt = 0; nt < 4; ++nt) {
                oacc[nt] = __builtin_amdgcn_mfma_f32_16x16x32_bf16(pa0, vf[nt], oacc[nt], 0, 0, 0);
                oacc[nt] = __builtin_amdgcn_mfma_f32_16x16x32_bf16(pa1, vf[4 + nt], oacc[nt], 0, 0, 0);
            }
            __builtin_amdgcn_s_setprio(0);
            // no trailing barrier: sync1(t+1) fences M-reads vs next M-writes;
            // P writes of t+1 are post-sync2(t) in program order for every wave.
        }

        // ---------- epilogue: normalized bf16 partial O + (m,l) for this seg ----------
        float lt = lrun;
        lt += __shfl_xor(lt, 16);
        lt += __shfl_xor(lt, 32);
        if (lg == 0)
            ppml[(((size_t)pairIdx * 2 + kpar) * 16 + g) * 16 + l15] = make_float2(mrun, lt);
        float rl = (lt > 0.f) ? (1.0f / lt) : 0.f;
        int rli = __builtin_bit_cast(int, rl);
        size_t obase = (((size_t)pairIdx * 2 + kpar) * 16 + g) * 1024;
#pragma unroll
        for (int r = 0; r < 4; ++r) {
            int v = __builtin_amdgcn_ds_bpermute((lg * 4 + r) * 4, rli);
            float linv = __builtin_bit_cast(float, v);
            int q = lg * 4 + r;
#pragma unroll
            for (int nt = 0; nt < 4; ++nt)
                ppO[obase + q * 64 + nt * 16 + l15] =
                    (unsigned short)f2bf(oacc[nt][r] * linv);
        }
        __syncthreads();   // LDS quiesce before next segment reuses P/M
    }
}

// ---------- combine: merge the 2 k-parity partials per (b,qt) ----------
__global__ __launch_bounds__(256) void hca_combine(
    const unsigned short* __restrict__ ppO, const float2* __restrict__ ppml,
    float* __restrict__ out)
{
    const int pairIdx = blockIdx.x;        // b*64 + qt
    const int b = pairIdx >> 6, qt = pairIdx & 63;
    const int t = threadIdx.x;
    const int g = t >> 4, dc = t & 15;

    const size_t o0 = (((size_t)pairIdx * 2 + 0) * 16 + g) * 1024;
    const size_t o1 = (((size_t)pairIdx * 2 + 1) * 16 + g) * 1024;
    const float2* ml0p = ppml + (((size_t)pairIdx * 2 + 0) * 16 + g) * 16;
    const float2* ml1p = ppml + (((size_t)pairIdx * 2 + 1) * 16 + g) * 16;

#pragma unroll 4
    for (int q = 0; q < 16; ++q) {
        float2 ml0 = ml0p[q], ml1 = ml1p[q];
        float ms = fmaxf(ml0.x, ml1.x);
        float w0 = ml0.y * exp2f(ml0.x - ms);
        float w1 = ml1.y * exp2f(ml1.x - ms);
        float rs = 1.0f / (w0 + w1);
        float a0 = w0 * rs, a1 = w1 * rs;
        ushort4 u0 = *reinterpret_cast<const ushort4*>(ppO + o0 + q * 64 + dc * 4);
        ushort4 u1 = *reinterpret_cast<const ushort4*>(ppO + o1 + q * 64 + dc * 4);
        float4 res;
        res.x = a0 * bfu(u0.x) + a1 * bfu(u1.x);
        res.y = a0 * bfu(u0.y) + a1 * bfu(u1.y);
        res.z = a0 * bfu(u0.z) + a1 * bfu(u1.z);
        res.w = a0 * bfu(u0.w) + a1 * bfu(u1.w);
        *reinterpret_cast<float4*>(out + (((size_t)b * SS + qt * 16 + q) * HH + g) * DD + dc * 4) = res;
    }
}

extern "C" void kernel_launch(void* const* d_in, const int* in_sizes, int n_in,
                              void* d_out, int out_size, void* d_ws, size_t ws_size,
                              hipStream_t stream) {
    const float* xq = (const float*)d_in[0];
    const float* xk = (const float*)d_in[1];
    const float* xv = (const float*)d_in[2];
    const float* Wm = (const float*)d_in[3];
    const int* causal = (const int*)d_in[4];
    float* out = (float*)d_out;

    short* vfr = (short*)d_ws;                               // 8 MB fragment-major V
    short* kfr = vfr + (size_t)NB * HH * SS * DD;            // 8 MB fragment-major K
    unsigned short* ppO = (unsigned short*)(kfr + (size_t)NB * HH * SS * DD);  // 16 MB
    float2* ppml = (float2*)(ppO + (size_t)512 * 16 * 1024); // 1 MB

    prep_kfrag<<<2048, 256, 0, stream>>>(xk, kfr);
    prep_vfrag<<<NB * HH * NKST, 256, 0, stream>>>(xv, vfr);

    hca_fused<<<256, 1024, 0, stream>>>(xq, kfr, vfr, Wm, causal, ppO, ppml);
    hca_combine<<<256, 256, 0, stream>>>(ppO, ppml, out);
}